// Round 12
// baseline (176.173 us; speedup 1.0000x reference)
//
#include <hip/hip_runtime.h>
#include <hip/hip_bf16.h>
#include <hip/hip_fp16.h>
#include <cstddef>

// ---------------------------------------------------------------------------
// GAT 2-layer forward. N=50000 nodes, E=800000 edges (+N self loops).
// R22 DECOMPOSITION PROBE #2: R15 base (154.2us). R21 duplicated the two
//      aggregates: dur 185.0 (+30.9) but FAILED post-timing refcheck
//      (mechanism unexplained — duplicates are dataflow-idempotent).
//      This round duplicates the two FRONT-END kernels (localsort,
//      csr_gemm1) instead — same 7-dispatch count as R21:
//        delta ~= +30 again -> per-dispatch overhead dominates (~15us each)
//        delta >= +60       -> front-end work dominates -> rewrite CSR build
//        failed again       -> duplication probes invalid in this harness
// ---------------------------------------------------------------------------

#define NNODES 50000
#define NEDGES 800000
#define FOUT   64
#define NBKT   512
#define BSPAN  98       // nodes per bucket (512*98 = 50176 >= 50000)
#define CHUNK  2048     // edges per localsort block (391 blocks)
#define REGS   2560     // csrc region stride per bucket (cap; mean ~1666)
#define NLBMAX 512      // >= number of localsort blocks (391)

__device__ __forceinline__ float leaky(float t) { return t > 0.f ? t : 0.2f * t; }
#define RL(v, j) __builtin_amdgcn_readlane((v), (j))

using half8  = __attribute__((ext_vector_type(8))) _Float16;
using half4v = __attribute__((ext_vector_type(4))) _Float16;
using f32x4  = __attribute__((ext_vector_type(4))) float;

// ---------------- stage 1: local counting sort by coarse bucket ------------

__global__ __launch_bounds__(256) void k_localsort(
    const int* __restrict__ ei, unsigned* __restrict__ gout,
    int* __restrict__ goff, int E)
{
    __shared__ unsigned lrec[CHUNK];   // s | d<<16 (both < 2^16)
    __shared__ unsigned lsrt[CHUNK];
    __shared__ int cnt[NBKT];
    __shared__ int cur[NBKT];
    __shared__ int exc[NBKT + 1];

    const int t = threadIdx.x;
    const int blk = blockIdx.x;
    const int e0 = blk * CHUNK;
    const int e1 = min(e0 + CHUNK, E);
    const int ne = e1 - e0;

    for (int i = t; i < NBKT; i += 256) cnt[i] = 0;
    __syncthreads();

    for (int i = e0 + t; i < e1; i += 256) {
        unsigned s = (unsigned)ei[i];
        unsigned d = (unsigned)ei[E + i];
        lrec[i - e0] = s | (d << 16);
        atomicAdd(&cnt[d / BSPAN], 1);
    }
    __syncthreads();

    // exclusive scan of cnt[512] by wave 0 (lane covers 8 bins)
    if (t < 64) {
        int c[8]; int s = 0;
        #pragma unroll
        for (int k = 0; k < 8; ++k) { c[k] = cnt[t * 8 + k]; s += c[k]; }
        int inc = s;
        #pragma unroll
        for (int d = 1; d < 64; d <<= 1) { int u = __shfl_up(inc, d); if (t >= d) inc += u; }
        int ex = inc - s;
        #pragma unroll
        for (int k = 0; k < 8; ++k) { exc[t * 8 + k] = ex; cur[t * 8 + k] = ex; ex += c[k]; }
        if (t == 63) exc[NBKT] = ex;
    }
    __syncthreads();

    for (int i = t; i < ne; i += 256) {
        unsigned r = lrec[i];
        unsigned d = r >> 16;
        unsigned b = d / BSPAN;
        int p = atomicAdd(&cur[b], 1);
        lsrt[p] = (r & 0xFFFFu) | ((d - b * BSPAN) << 16);
    }
    __syncthreads();

    for (int i = t; i < ne; i += 256) gout[e0 + i] = lsrt[i];       // coalesced
    for (int i = t; i < NBKT + 1; i += 256)
        goff[blk * (NBKT + 1) + i] = e0 + exc[i];
}

// ---------------- per-bucket exact CSR (device body, dynamic LDS) ----------

__device__ __forceinline__ void csr_body(
    char* smem, int bkt,
    const unsigned* __restrict__ gout, const int* __restrict__ goff,
    int* __restrict__ csrc, int2* __restrict__ rowse,
    int n, int nlb)
{
    unsigned* ltmp  = (unsigned*)smem;                          // REGS
    int* lout  = (int*)(smem + REGS * 4);                       // REGS
    int* lcnt  = (int*)(smem + 2 * REGS * 4);                   // BSPAN
    int* lbase = lcnt + BSPAN;                                  // BSPAN+1
    int* lcur  = lbase + BSPAN + 1;                             // BSPAN
    int* rg0   = lcur + BSPAN;                                  // NLBMAX
    int* rlen  = rg0 + NLBMAX;                                  // NLBMAX
    int* rbase = rlen + NLBMAX;                                 // NLBMAX+1

    const int t = threadIdx.x;
    const int node0 = bkt * BSPAN;
    if (node0 >= n) return;
    const int nn = min(BSPAN, n - node0);

    for (int i = t; i < BSPAN; i += 256) lcnt[i] = (i < nn) ? 1 : 0;  // self loop
    for (int i = t; i < nlb; i += 256) {
        int g0 = goff[i * (NBKT + 1) + bkt];
        int g1 = goff[i * (NBKT + 1) + bkt + 1];
        rg0[i] = g0;
        rlen[i] = g1 - g0;
    }
    __syncthreads();

    // exclusive scan of rlen[nlb<=512] by wave 0 (lane covers 8 entries)
    if (t < 64) {
        int c[8]; int s = 0;
        #pragma unroll
        for (int k = 0; k < 8; ++k) {
            int idx = t * 8 + k;
            c[k] = (idx < nlb) ? rlen[idx] : 0;
            s += c[k];
        }
        int inc = s;
        #pragma unroll
        for (int d = 1; d < 64; d <<= 1) { int u = __shfl_up(inc, d); if (t >= d) inc += u; }
        int ex = inc - s;
        #pragma unroll
        for (int k = 0; k < 8; ++k) { rbase[t * 8 + k] = ex; ex += c[k]; }
        if (t == 63) rbase[NLBMAX] = ex;
    }
    __syncthreads();

    const int tot = min(rbase[nlb], REGS - BSPAN);

    // thread-per-record gather: binary search run, copy
    for (int i = t; i < tot; i += 256) {
        int lo = 0, hi = nlb;
        while (hi - lo > 1) {
            int mid = (lo + hi) >> 1;
            if (rbase[mid] <= i) lo = mid; else hi = mid;
        }
        ltmp[i] = gout[rg0[lo] + (i - rbase[lo])];
    }
    __syncthreads();

    for (int i = t; i < tot; i += 256) atomicAdd(&lcnt[ltmp[i] >> 16], 1);
    __syncthreads();

    // exclusive scan of lcnt[98] by wave 0 (lane covers 2 bins)
    if (t < 64) {
        int b0 = t * 2, b1 = t * 2 + 1;
        int c0 = (b0 < BSPAN) ? lcnt[b0] : 0;
        int c1 = (b1 < BSPAN) ? lcnt[b1] : 0;
        int s = c0 + c1;
        int inc = s;
        #pragma unroll
        for (int d = 1; d < 64; d <<= 1) { int u = __shfl_up(inc, d); if (t >= d) inc += u; }
        int ex = inc - s;
        if (b0 < BSPAN) { lbase[b0] = ex;      lcur[b0] = ex + 1; }      // slot 0 = self
        if (b1 < BSPAN) { lbase[b1] = ex + c0; lcur[b1] = ex + c0 + 1; }
        if (t == 63) lbase[BSPAN] = inc;
    }
    __syncthreads();

    for (int i = t; i < nn; i += 256) lout[lbase[i]] = node0 + i;    // self loops
    for (int i = t; i < tot; i += 256) {
        unsigned r = ltmp[i];
        int p = atomicAdd(&lcur[r >> 16], 1);
        lout[p] = (int)(r & 0xFFFFu);
    }
    __syncthreads();

    const int gbase = bkt * REGS;
    const int total = tot + nn;
    for (int i = t; i < total; i += 256) csrc[gbase + i] = lout[i];  // coalesced
    for (int i = t; i < nn; i += 256)
        rowse[node0 + i] = make_int2(gbase + lbase[i], gbase + lbase[i + 1]);
}

// ---------------- MFMA GEMM + alpha (device body, dynamic LDS) -------------

template <int K, typename XT>
__device__ __forceinline__ void gemm_body(
    char* smem, int bx,
    const XT* __restrict__ x, const float* __restrict__ W,
    const float* __restrict__ a_src, const float* __restrict__ a_dst,
    __half* __restrict__ h16, float* __restrict__ as_, float* __restrict__ ad_, int n)
{
    constexpr int KP = K + 8;                 // row stride in halves; 2*KP % 16 == 0
    _Float16* Ah = (_Float16*)smem;           // 64 * KP
    _Float16* Wf = (_Float16*)(smem + 64 * KP * 2);  // K * 64, fragment layout

    const int t    = threadIdx.x;
    const int lane = t & 63;
    const int wv   = t >> 6;
    const int n16  = lane & 15;
    const int quad = lane >> 4;
    const int r0   = bx * 64;

    // stage W in B-fragment layout: Wf[((k>>3)*64 + c)*8 + (k&7)]
    for (int i = t; i < K * 64; i += 256) {
        int k = i >> 6, c = i & 63;
        Wf[((k >> 3) * 64 + c) * 8 + (k & 7)] = (_Float16)W[i];
    }
    // stage x rows as fp16
    if constexpr (sizeof(XT) == 4) {
        constexpr int KQ = K / 4;
        for (int i = t; i < 64 * KQ; i += 256) {
            int r = i / KQ, kq = i % KQ;
            int row = r0 + r;
            float4 v = make_float4(0.f, 0.f, 0.f, 0.f);
            if (row < n) v = ((const float4*)(x + (size_t)row * K))[kq];
            half4v hv = { (_Float16)v.x, (_Float16)v.y, (_Float16)v.z, (_Float16)v.w };
            *(half4v*)&Ah[r * KP + kq * 4] = hv;
        }
    } else {
        constexpr int KO = K / 8;
        for (int i = t; i < 64 * KO; i += 256) {
            int r = i / KO, ko = i % KO;
            int row = r0 + r;
            half8 hv = {};
            if (row < n) hv = *(const half8*)((const _Float16*)x + (size_t)row * K + ko * 8);
            *(half8*)&Ah[r * KP + ko * 8] = hv;
        }
    }
    __syncthreads();

    // preload all B fragments (block-uniform W)
    half8 bfr[K / 32][4];
    #pragma unroll
    for (int kk = 0; kk < K / 32; ++kk)
        #pragma unroll
        for (int ct = 0; ct < 4; ++ct)
            bfr[kk][ct] = *(const half8*)&Wf[((kk * 4 + quad) * 64 + ct * 16 + n16) * 8];

    f32x4 acc[4];
    #pragma unroll
    for (int ct = 0; ct < 4; ++ct) acc[ct] = (f32x4){0.f, 0.f, 0.f, 0.f};

    #pragma unroll
    for (int kk = 0; kk < K / 32; ++kk) {
        half8 a = *(const half8*)&Ah[(wv * 16 + n16) * KP + kk * 32 + quad * 8];
        #pragma unroll
        for (int ct = 0; ct < 4; ++ct)
            acc[ct] = __builtin_amdgcn_mfma_f32_16x16x32_f16(a, bfr[kk][ct], acc[ct], 0, 0, 0);
    }

    // epilogue: alpha dots off fp32 accumulators + fp16 h store
    const int rowb = r0 + wv * 16 + quad * 4;
    float asv[4], adv[4];
    #pragma unroll
    for (int ct = 0; ct < 4; ++ct) {
        asv[ct] = a_src[ct * 16 + n16];
        adv[ct] = a_dst[ct * 16 + n16];
    }
    float pa[4] = {0.f, 0.f, 0.f, 0.f}, pd[4] = {0.f, 0.f, 0.f, 0.f};
    #pragma unroll
    for (int ct = 0; ct < 4; ++ct)
        #pragma unroll
        for (int r = 0; r < 4; ++r) {
            pa[r] = fmaf(acc[ct][r], asv[ct], pa[r]);
            pd[r] = fmaf(acc[ct][r], adv[ct], pd[r]);
        }
    #pragma unroll
    for (int r = 0; r < 4; ++r) {
        #pragma unroll
        for (int d = 1; d <= 8; d <<= 1) {
            pa[r] += __shfl_xor(pa[r], d);
            pd[r] += __shfl_xor(pd[r], d);
        }
    }
    if (n16 == 0) {
        #pragma unroll
        for (int r = 0; r < 4; ++r) {
            if (rowb + r < n) { as_[rowb + r] = pa[r]; ad_[rowb + r] = pd[r]; }
        }
    }

    _Float16* hh = (_Float16*)h16;
    #pragma unroll
    for (int r = 0; r < 4; ++r) {
        if (rowb + r < n) {
            #pragma unroll
            for (int ct = 0; ct < 4; ++ct)
                hh[(size_t)(rowb + r) * 64 + ct * 16 + n16] = (_Float16)acc[ct][r];
        }
    }
}

// ---------------- fused launch 2: [csr buckets | gemm layer 1] -------------

__global__ __launch_bounds__(256) void k_csr_gemm1(
    const unsigned* __restrict__ gout, const int* __restrict__ goff,
    int* __restrict__ csrc, int2* __restrict__ rowse, int nlb,
    const float* __restrict__ x, const float* __restrict__ W1,
    const float* __restrict__ a1s, const float* __restrict__ a1d,
    __half* __restrict__ h16, float* __restrict__ as_, float* __restrict__ ad_, int n)
{
    extern __shared__ __align__(16) char smem[];
    if (blockIdx.x < NBKT)
        csr_body(smem, blockIdx.x, gout, goff, csrc, rowse, n, nlb);
    else
        gemm_body<128, float>(smem, blockIdx.x - NBKT, x, W1, a1s, a1d, h16, as_, ad_, n);
}

__global__ __launch_bounds__(256) void k_gemm2(
    const __half* __restrict__ xh, const float* __restrict__ W2,
    const float* __restrict__ a2s, const float* __restrict__ a2d,
    __half* __restrict__ h16, float* __restrict__ as_, float* __restrict__ ad_, int n)
{
    extern __shared__ __align__(16) char smem[];
    gemm_body<64, _Float16>(smem, blockIdx.x, (const _Float16*)xh, W2, a2s, a2d, h16, as_, ad_, n);
}

// ---------------- per-dst aggregation (two nodes per wave) -----------------

#define SHF(v, l) __shfl((v), (l))

template <bool RELU, typename OT>
__device__ __forceinline__ void agg_one(
    int node, int lane,
    const int2* __restrict__ rowse,
    const int* __restrict__ csrc, const __half* __restrict__ h16,
    const float* __restrict__ as_, const float* __restrict__ ad_,
    const float* __restrict__ bias, OT* __restrict__ out)
{
    const int2 se = rowse[node];
    const int start = se.x;
    const int end   = se.y;
    const int deg   = end - start;
    const float adn = ad_[node];

    if (deg <= 64) {
        int s = 0;
        if (lane < deg) s = csrc[start + lane];
        const int myoff = s << 6;

        const int g  = lane >> 3;
        const int fl = (lane & 7) << 3;
        const __half* __restrict__ hf = h16 + fl;
        const int niter = (deg + 7) >> 3;

        uint4 v[8];
        #pragma unroll
        for (int j = 0; j < 8; ++j) {
            if (j < niter)
                v[j] = *(const uint4*)(hf + SHF(myoff, (j << 3) + g));
        }

        float e = -1e30f;
        if (lane < deg) e = leaky(as_[s] + adn);
        float w = __expf(e);            // pad lanes: exp(-1e30)=0
        float dsum = w;
        #pragma unroll
        for (int d = 32; d >= 1; d >>= 1) dsum += __shfl_xor(dsum, d);

        float af[8] = {0.f, 0.f, 0.f, 0.f, 0.f, 0.f, 0.f, 0.f};
        #pragma unroll
        for (int j = 0; j < 8; ++j) {
            if (j < niter) {
                float wj = SHF(w, (j << 3) + g);
                unsigned uu[4] = {v[j].x, v[j].y, v[j].z, v[j].w};
                #pragma unroll
                for (int q = 0; q < 4; ++q) {
                    __half2 h2 = *(__half2*)&uu[q];
                    float2 f2 = __half22float2(h2);
                    af[2 * q]     = fmaf(wj, f2.x, af[2 * q]);
                    af[2 * q + 1] = fmaf(wj, f2.y, af[2 * q + 1]);
                }
            }
        }
        #pragma unroll
        for (int q = 0; q < 8; ++q) {
            af[q] += __shfl_xor(af[q], 8);
            af[q] += __shfl_xor(af[q], 16);
            af[q] += __shfl_xor(af[q], 32);
        }
        if (g == 0) {
            float inv = 1.f / dsum;
            float4 b0 = *(const float4*)(bias + fl);
            float4 b1 = *(const float4*)(bias + fl + 4);
            float o[8] = { fmaf(af[0], inv, b0.x), fmaf(af[1], inv, b0.y),
                           fmaf(af[2], inv, b0.z), fmaf(af[3], inv, b0.w),
                           fmaf(af[4], inv, b1.x), fmaf(af[5], inv, b1.y),
                           fmaf(af[6], inv, b1.z), fmaf(af[7], inv, b1.w) };
            if (RELU) {
                #pragma unroll
                for (int q = 0; q < 8; ++q) o[q] = fmaxf(o[q], 0.f);
            }
            if constexpr (sizeof(OT) == 2) {
                __half* op = (__half*)out + (size_t)node * 64 + fl;
                __half2 p0 = __floats2half2_rn(o[0], o[1]);
                __half2 p1 = __floats2half2_rn(o[2], o[3]);
                __half2 p2 = __floats2half2_rn(o[4], o[5]);
                __half2 p3 = __floats2half2_rn(o[6], o[7]);
                uint4 pk = { *(unsigned*)&p0, *(unsigned*)&p1, *(unsigned*)&p2, *(unsigned*)&p3 };
                *(uint4*)op = pk;
            } else {
                float* op = (float*)out + (size_t)node * 64 + fl;
                *(float4*)op       = make_float4(o[0], o[1], o[2], o[3]);
                *(float4*)(op + 4) = make_float4(o[4], o[5], o[6], o[7]);
            }
        }
    } else {
        const __half* __restrict__ hp = h16 + lane;
        float m = -1e30f;
        for (int base = start; base < end; base += 64) {
            int idx = base + lane;
            if (idx < end) m = fmaxf(m, leaky(as_[csrc[idx]] + adn));
        }
        #pragma unroll
        for (int d = 32; d >= 1; d >>= 1) m = fmaxf(m, __shfl_xor(m, d));

        float acc0 = 0.f, acc1 = 0.f, acc2 = 0.f, acc3 = 0.f, dsum = 0.f;
        for (int base = start; base < end; base += 64) {
            int idx = base + lane;
            int s = 0; float w = 0.f;
            if (idx < end) {
                s = csrc[idx];
                w = __expf(leaky(as_[s] + adn) - m);
            }
            dsum += w;
            int off = s << 6;
            int wu = __float_as_uint(w);
            int cnt = min(64, end - base);
            int cr = (cnt + 3) & ~3;
            for (int j = 0; j < cr; j += 4) {
                int   o0 = RL(off, j + 0), o1 = RL(off, j + 1);
                int   o2 = RL(off, j + 2), o3 = RL(off, j + 3);
                float w0 = __uint_as_float(RL(wu, j + 0));
                float w1 = __uint_as_float(RL(wu, j + 1));
                float w2 = __uint_as_float(RL(wu, j + 2));
                float w3 = __uint_as_float(RL(wu, j + 3));
                float v0 = __half2float(hp[o0]), v1 = __half2float(hp[o1]);
                float v2 = __half2float(hp[o2]), v3 = __half2float(hp[o3]);
                acc0 = fmaf(w0, v0, acc0);
                acc1 = fmaf(w1, v1, acc1);
                acc2 = fmaf(w2, v2, acc2);
                acc3 = fmaf(w3, v3, acc3);
            }
        }
        #pragma unroll
        for (int d = 32; d >= 1; d >>= 1) dsum += __shfl_xor(dsum, d);
        float acc = (acc0 + acc1) + (acc2 + acc3);
        float o = acc / dsum + bias[lane];
        if (RELU) o = fmaxf(o, 0.f);
        if constexpr (sizeof(OT) == 2)
            ((__half*)out)[(size_t)node * 64 + lane] = __float2half(o);
        else
            ((float*)out)[(size_t)node * 64 + lane] = o;
    }
}

template <bool RELU, typename OT>
__global__ __launch_bounds__(256) void k_aggregate(
    const int2* __restrict__ rowse,
    const int* __restrict__ csrc,
    const __half* __restrict__ h16, const float* __restrict__ as_,
    const float* __restrict__ ad_, const float* __restrict__ bias,
    OT* __restrict__ out, int n)
{
    const int lane = threadIdx.x & 63;
    const int wid  = threadIdx.x >> 6;
    const int nodeA = (blockIdx.x * 4 + wid) * 2;
    if (nodeA >= n) return;

    const int half = lane >> 5;
    const int hl   = lane & 31;
    const int node = nodeA + half;           // n is even: nodeA+1 < n

    const int2 se = rowse[node];
    const float adn = ad_[node];             // independent: issue early
    const int start = se.x;
    const int deg   = se.y - se.x;
    const int mdeg  = max(deg, __shfl_xor(deg, 32));   // wave-uniform

    if (mdeg <= 32) {
        // ---- paired fast path: 32 lanes per node ----
        int s = 0;
        const bool act = hl < deg;
        if (act) s = csrc[start + hl];
        const int myoff = s << 6;

        const int g  = (lane >> 3) & 3;      // group within half
        const int fl = (lane & 7) << 3;      // feature octet
        const __half* __restrict__ hf = h16 + fl;
        int nit = (deg + 3) >> 2;            // 1..8
        nit = max(nit, __shfl_xor(nit, 32)); // wave-uniform

        // issue ALL h-row loads (offsets via bpermute, no LDS round trip)
        const int sbase = (half << 5) + g;
        uint4 v[8];
        #pragma unroll
        for (int j = 0; j < 8; ++j) {
            if (j < nit)
                v[j] = *(const uint4*)(hf + SHF(myoff, sbase + (j << 2)));
        }

        // w chain overlaps the in-flight h loads
        float e = -1e30f;                    // exp(-1e30) = 0 for pad lanes
        if (act) e = leaky(as_[s] + adn);
        float w = __expf(e);
        float dsum = w;
        #pragma unroll
        for (int d = 16; d >= 1; d >>= 1) dsum += __shfl_xor(dsum, d);

        float af[8] = {0.f, 0.f, 0.f, 0.f, 0.f, 0.f, 0.f, 0.f};
        #pragma unroll
        for (int j = 0; j < 8; ++j) {
            if (j < nit) {
                float wj = SHF(w, sbase + (j << 2));
                unsigned uu[4] = {v[j].x, v[j].y, v[j].z, v[j].w};
                #pragma unroll
                for (int q = 0; q < 4; ++q) {
                    __half2 h2 = *(__half2*)&uu[q];
                    float2 f2 = __half22float2(h2);
                    af[2 * q]     = fmaf(wj, f2.x, af[2 * q]);
                    af[2 * q + 1] = fmaf(wj, f2.y, af[2 * q + 1]);
                }
            }
        }
        #pragma unroll
        for (int q = 0; q < 8; ++q) {
            af[q] += __shfl_xor(af[q], 8);
            af[q] += __shfl_xor(af[q], 16);
        }
        if (g == 0) {                        // lanes 0-7 (A) and 32-39 (B)
            float inv = 1.f / dsum;
            float4 b0 = *(const float4*)(bias + fl);
            float4 b1 = *(const float4*)(bias + fl + 4);
            float o[8] = { fmaf(af[0], inv, b0.x), fmaf(af[1], inv, b0.y),
                           fmaf(af[2], inv, b0.z), fmaf(af[3], inv, b0.w),
                           fmaf(af[4], inv, b1.x), fmaf(af[5], inv, b1.y),
                           fmaf(af[6], inv, b1.z), fmaf(af[7], inv, b1.w) };
            if (RELU) {
                #pragma unroll
                for (int q = 0; q < 8; ++q) o[q] = fmaxf(o[q], 0.f);
            }
            if constexpr (sizeof(OT) == 2) {
                __half* op = (__half*)out + (size_t)node * 64 + fl;
                __half2 p0 = __floats2half2_rn(o[0], o[1]);
                __half2 p1 = __floats2half2_rn(o[2], o[3]);
                __half2 p2 = __floats2half2_rn(o[4], o[5]);
                __half2 p3 = __floats2half2_rn(o[6], o[7]);
                uint4 pk = { *(unsigned*)&p0, *(unsigned*)&p1, *(unsigned*)&p2, *(unsigned*)&p3 };
                *(uint4*)op = pk;
            } else {
                float* op = (float*)out + (size_t)node * 64 + fl;
                *(float4*)op       = make_float4(o[0], o[1], o[2], o[3]);
                *(float4*)(op + 4) = make_float4(o[4], o[5], o[6], o[7]);
            }
        }
    } else {
        agg_one<RELU, OT>(nodeA,     lane, rowse, csrc, h16, as_, ad_, bias, out);
        agg_one<RELU, OT>(nodeA + 1, lane, rowse, csrc, h16, as_, ad_, bias, out);
    }
}

// ---------------- launch ----------------

extern "C" void kernel_launch(void* const* d_in, const int* in_sizes, int n_in,
                              void* d_out, int out_size, void* d_ws, size_t ws_size,
                              hipStream_t stream) {
    const float* x   = (const float*)d_in[0];
    const int*   ei  = (const int*)  d_in[1];   // [2, E]: src row 0, dst row 1
    const float* W1  = (const float*)d_in[2];
    const float* a1s = (const float*)d_in[3];
    const float* a1d = (const float*)d_in[4];
    const float* b1  = (const float*)d_in[5];
    const float* W2  = (const float*)d_in[6];
    const float* a2s = (const float*)d_in[7];
    const float* a2d = (const float*)d_in[8];
    const float* b2  = (const float*)d_in[9];
    float* out = (float*)d_out;

    const int N_ = NNODES, E_ = NEDGES;
    const int NLB = (E_ + CHUNK - 1) / CHUNK;   // 391

    char* ws = (char*)d_ws;
    size_t off = 0;
    auto alloc = [&](size_t bytes) -> void* {
        void* p = ws + off;
        off += (bytes + 255) & ~(size_t)255;
        return p;
    };
    int*      csrc     = (int*)alloc((size_t)NBKT * REGS * 4);     // 5.24 MB
    int2*     rowse    = (int2*)alloc((size_t)N_ * 8);
    float*    as_      = (float*)alloc((size_t)N_ * 4);
    float*    ad_      = (float*)alloc((size_t)N_ * 4);
    __half*   h16      = (__half*)alloc((size_t)N_ * FOUT * 2);    // 6.4 MB
    __half*   xr2h     = (__half*)alloc((size_t)N_ * FOUT * 2);    // 6.4 MB
    unsigned* gout     = (unsigned*)alloc((size_t)E_ * 4);         // 3.2 MB
    int*      goff     = (int*)alloc((size_t)NLB * (NBKT + 1) * 4);

    constexpr unsigned SM_G1 = 64 * (128 + 8) * 2 + 128 * 64 * 2;  // 33792 B (>= csr carve)
    constexpr unsigned SM_G2 = 64 * (64 + 8) * 2  + 64 * 64 * 2;   // 17408 B

    const int GB = (N_ + 63) / 64;     // 782 gemm blocks
    const int AB = (N_ / 2 + 3) / 4;   // 6250 aggregate blocks (2 nodes/wave)

    // PROBE: front-end dispatched TWICE (both are pure functions of their
    // inputs) — delta vs 154.2us = T_localsort + T_csr_gemm1 (warm).
    k_localsort<<<NLB, 256, 0, stream>>>(ei, gout, goff, E_);
    k_localsort<<<NLB, 256, 0, stream>>>(ei, gout, goff, E_);
    k_csr_gemm1<<<NBKT + GB, 256, SM_G1, stream>>>(gout, goff, csrc, rowse, NLB,
                                                   x, W1, a1s, a1d, h16, as_, ad_, N_);
    k_csr_gemm1<<<NBKT + GB, 256, SM_G1, stream>>>(gout, goff, csrc, rowse, NLB,
                                                   x, W1, a1s, a1d, h16, as_, ad_, N_);
    k_aggregate<true,  __half><<<AB, 256, 0, stream>>>(rowse, csrc, h16, as_, ad_, b1, xr2h, N_);
    k_gemm2<<<GB, 256, SM_G2, stream>>>(xr2h, W2, a2s, a2d, h16, as_, ad_, N_);
    k_aggregate<false, float ><<<AB, 256, 0, stream>>>(rowse, csrc, h16, as_, ad_, b2, out, N_);
}

// Round 18
// 153.553 us; speedup vs baseline: 1.1473x; 1.1473x over previous
//
#include <hip/hip_runtime.h>
#include <hip/hip_bf16.h>
#include <hip/hip_fp16.h>
#include <cstddef>

// ---------------------------------------------------------------------------
// GAT 2-layer forward. N=50000 nodes, E=800000 edges (+N self loops).
// R28: re-submit of R27 (== R15, measured 154.17us, passed) after another
//      GPUAcquisitionTimeout. This is the best harness-verified kernel.
//      Session ledger: fusions +13.6/+8.6 (reverted), parallelism/broadcast
//      null, fp8-h1 accuracy-fail (0.078 > 0.0369). Decomposition puts the
//      pipeline within ~3-12% of its structural floor (cold aggregates are
//      L3-random-gather-throughput bound; front-end scan-bound).
// ---------------------------------------------------------------------------

#define NNODES 50000
#define NEDGES 800000
#define FOUT   64
#define NBKT   512
#define BSPAN  98       // nodes per bucket (512*98 = 50176 >= 50000)
#define CHUNK  2048     // edges per localsort block (391 blocks)
#define REGS   2560     // csrc region stride per bucket (cap; mean ~1666)
#define NLBMAX 512      // >= number of localsort blocks (391)

__device__ __forceinline__ float leaky(float t) { return t > 0.f ? t : 0.2f * t; }
#define RL(v, j) __builtin_amdgcn_readlane((v), (j))
#define SHF(v, l) __shfl((v), (l))

using half8  = __attribute__((ext_vector_type(8))) _Float16;
using half4v = __attribute__((ext_vector_type(4))) _Float16;
using f32x4  = __attribute__((ext_vector_type(4))) float;

// ---------------- stage 1: local counting sort by coarse bucket ------------

__global__ __launch_bounds__(256) void k_localsort(
    const int* __restrict__ ei, unsigned* __restrict__ gout,
    int* __restrict__ goff, int E)
{
    __shared__ unsigned lrec[CHUNK];   // s | d<<16 (both < 2^16)
    __shared__ unsigned lsrt[CHUNK];
    __shared__ int cnt[NBKT];
    __shared__ int cur[NBKT];
    __shared__ int exc[NBKT + 1];

    const int t = threadIdx.x;
    const int blk = blockIdx.x;
    const int e0 = blk * CHUNK;
    const int e1 = min(e0 + CHUNK, E);
    const int ne = e1 - e0;

    for (int i = t; i < NBKT; i += 256) cnt[i] = 0;
    __syncthreads();

    for (int i = e0 + t; i < e1; i += 256) {
        unsigned s = (unsigned)ei[i];
        unsigned d = (unsigned)ei[E + i];
        lrec[i - e0] = s | (d << 16);
        atomicAdd(&cnt[d / BSPAN], 1);
    }
    __syncthreads();

    // exclusive scan of cnt[512] by wave 0 (lane covers 8 bins)
    if (t < 64) {
        int c[8]; int s = 0;
        #pragma unroll
        for (int k = 0; k < 8; ++k) { c[k] = cnt[t * 8 + k]; s += c[k]; }
        int inc = s;
        #pragma unroll
        for (int d = 1; d < 64; d <<= 1) { int u = __shfl_up(inc, d); if (t >= d) inc += u; }
        int ex = inc - s;
        #pragma unroll
        for (int k = 0; k < 8; ++k) { exc[t * 8 + k] = ex; cur[t * 8 + k] = ex; ex += c[k]; }
        if (t == 63) exc[NBKT] = ex;
    }
    __syncthreads();

    for (int i = t; i < ne; i += 256) {
        unsigned r = lrec[i];
        unsigned d = r >> 16;
        unsigned b = d / BSPAN;
        int p = atomicAdd(&cur[b], 1);
        lsrt[p] = (r & 0xFFFFu) | ((d - b * BSPAN) << 16);
    }
    __syncthreads();

    for (int i = t; i < ne; i += 256) gout[e0 + i] = lsrt[i];       // coalesced
    for (int i = t; i < NBKT + 1; i += 256)
        goff[blk * (NBKT + 1) + i] = e0 + exc[i];
}

// ---------------- per-bucket exact CSR (device body, dynamic LDS) ----------

__device__ __forceinline__ void csr_body(
    char* smem, int bkt,
    const unsigned* __restrict__ gout, const int* __restrict__ goff,
    int* __restrict__ csrc, int2* __restrict__ rowse,
    int n, int nlb)
{
    unsigned* ltmp  = (unsigned*)smem;                          // REGS
    int* lout  = (int*)(smem + REGS * 4);                       // REGS
    int* lcnt  = (int*)(smem + 2 * REGS * 4);                   // BSPAN
    int* lbase = lcnt + BSPAN;                                  // BSPAN+1
    int* lcur  = lbase + BSPAN + 1;                             // BSPAN
    int* rg0   = lcur + BSPAN;                                  // NLBMAX
    int* rlen  = rg0 + NLBMAX;                                  // NLBMAX
    int* rbase = rlen + NLBMAX;                                 // NLBMAX+1

    const int t = threadIdx.x;
    const int node0 = bkt * BSPAN;
    if (node0 >= n) return;
    const int nn = min(BSPAN, n - node0);

    for (int i = t; i < BSPAN; i += 256) lcnt[i] = (i < nn) ? 1 : 0;  // self loop
    for (int i = t; i < nlb; i += 256) {
        int g0 = goff[i * (NBKT + 1) + bkt];
        int g1 = goff[i * (NBKT + 1) + bkt + 1];
        rg0[i] = g0;
        rlen[i] = g1 - g0;
    }
    __syncthreads();

    // exclusive scan of rlen[nlb<=512] by wave 0 (lane covers 8 entries)
    if (t < 64) {
        int c[8]; int s = 0;
        #pragma unroll
        for (int k = 0; k < 8; ++k) {
            int idx = t * 8 + k;
            c[k] = (idx < nlb) ? rlen[idx] : 0;
            s += c[k];
        }
        int inc = s;
        #pragma unroll
        for (int d = 1; d < 64; d <<= 1) { int u = __shfl_up(inc, d); if (t >= d) inc += u; }
        int ex = inc - s;
        #pragma unroll
        for (int k = 0; k < 8; ++k) { rbase[t * 8 + k] = ex; ex += c[k]; }
        if (t == 63) rbase[NLBMAX] = ex;
    }
    __syncthreads();

    const int tot = min(rbase[nlb], REGS - BSPAN);

    // thread-per-record gather: binary search run, copy
    for (int i = t; i < tot; i += 256) {
        int lo = 0, hi = nlb;
        while (hi - lo > 1) {
            int mid = (lo + hi) >> 1;
            if (rbase[mid] <= i) lo = mid; else hi = mid;
        }
        ltmp[i] = gout[rg0[lo] + (i - rbase[lo])];
    }
    __syncthreads();

    for (int i = t; i < tot; i += 256) atomicAdd(&lcnt[ltmp[i] >> 16], 1);
    __syncthreads();

    // exclusive scan of lcnt[98] by wave 0 (lane covers 2 bins)
    if (t < 64) {
        int b0 = t * 2, b1 = t * 2 + 1;
        int c0 = (b0 < BSPAN) ? lcnt[b0] : 0;
        int c1 = (b1 < BSPAN) ? lcnt[b1] : 0;
        int s = c0 + c1;
        int inc = s;
        #pragma unroll
        for (int d = 1; d < 64; d <<= 1) { int u = __shfl_up(inc, d); if (t >= d) inc += u; }
        int ex = inc - s;
        if (b0 < BSPAN) { lbase[b0] = ex;      lcur[b0] = ex + 1; }      // slot 0 = self
        if (b1 < BSPAN) { lbase[b1] = ex + c0; lcur[b1] = ex + c0 + 1; }
        if (t == 63) lbase[BSPAN] = inc;
    }
    __syncthreads();

    for (int i = t; i < nn; i += 256) lout[lbase[i]] = node0 + i;    // self loops
    for (int i = t; i < tot; i += 256) {
        unsigned r = ltmp[i];
        int p = atomicAdd(&lcur[r >> 16], 1);
        lout[p] = (int)(r & 0xFFFFu);
    }
    __syncthreads();

    const int gbase = bkt * REGS;
    const int total = tot + nn;
    for (int i = t; i < total; i += 256) csrc[gbase + i] = lout[i];  // coalesced
    for (int i = t; i < nn; i += 256)
        rowse[node0 + i] = make_int2(gbase + lbase[i], gbase + lbase[i + 1]);
}

// ---------------- MFMA GEMM + alpha (device body, dynamic LDS) -------------

template <int K, typename XT>
__device__ __forceinline__ void gemm_body(
    char* smem, int bx,
    const XT* __restrict__ x, const float* __restrict__ W,
    const float* __restrict__ a_src, const float* __restrict__ a_dst,
    __half* __restrict__ h16, float* __restrict__ as_, float* __restrict__ ad_, int n)
{
    constexpr int KP = K + 8;                 // row stride in halves; 2*KP % 16 == 0
    _Float16* Ah = (_Float16*)smem;           // 64 * KP
    _Float16* Wf = (_Float16*)(smem + 64 * KP * 2);  // K * 64, fragment layout

    const int t    = threadIdx.x;
    const int lane = t & 63;
    const int wv   = t >> 6;
    const int n16  = lane & 15;
    const int quad = lane >> 4;
    const int r0   = bx * 64;

    // stage W in B-fragment layout: Wf[((k>>3)*64 + c)*8 + (k&7)]
    for (int i = t; i < K * 64; i += 256) {
        int k = i >> 6, c = i & 63;
        Wf[((k >> 3) * 64 + c) * 8 + (k & 7)] = (_Float16)W[i];
    }
    // stage x rows as fp16
    if constexpr (sizeof(XT) == 4) {
        constexpr int KQ = K / 4;
        for (int i = t; i < 64 * KQ; i += 256) {
            int r = i / KQ, kq = i % KQ;
            int row = r0 + r;
            float4 v = make_float4(0.f, 0.f, 0.f, 0.f);
            if (row < n) v = ((const float4*)(x + (size_t)row * K))[kq];
            half4v hv = { (_Float16)v.x, (_Float16)v.y, (_Float16)v.z, (_Float16)v.w };
            *(half4v*)&Ah[r * KP + kq * 4] = hv;
        }
    } else {
        constexpr int KO = K / 8;
        for (int i = t; i < 64 * KO; i += 256) {
            int r = i / KO, ko = i % KO;
            int row = r0 + r;
            half8 hv = {};
            if (row < n) hv = *(const half8*)((const _Float16*)x + (size_t)row * K + ko * 8);
            *(half8*)&Ah[r * KP + ko * 8] = hv;
        }
    }
    __syncthreads();

    // preload all B fragments (block-uniform W)
    half8 bfr[K / 32][4];
    #pragma unroll
    for (int kk = 0; kk < K / 32; ++kk)
        #pragma unroll
        for (int ct = 0; ct < 4; ++ct)
            bfr[kk][ct] = *(const half8*)&Wf[((kk * 4 + quad) * 64 + ct * 16 + n16) * 8];

    f32x4 acc[4];
    #pragma unroll
    for (int ct = 0; ct < 4; ++ct) acc[ct] = (f32x4){0.f, 0.f, 0.f, 0.f};

    #pragma unroll
    for (int kk = 0; kk < K / 32; ++kk) {
        half8 a = *(const half8*)&Ah[(wv * 16 + n16) * KP + kk * 32 + quad * 8];
        #pragma unroll
        for (int ct = 0; ct < 4; ++ct)
            acc[ct] = __builtin_amdgcn_mfma_f32_16x16x32_f16(a, bfr[kk][ct], acc[ct], 0, 0, 0);
    }

    // epilogue: alpha dots off fp32 accumulators + fp16 h store
    const int rowb = r0 + wv * 16 + quad * 4;
    float asv[4], adv[4];
    #pragma unroll
    for (int ct = 0; ct < 4; ++ct) {
        asv[ct] = a_src[ct * 16 + n16];
        adv[ct] = a_dst[ct * 16 + n16];
    }
    float pa[4] = {0.f, 0.f, 0.f, 0.f}, pd[4] = {0.f, 0.f, 0.f, 0.f};
    #pragma unroll
    for (int ct = 0; ct < 4; ++ct)
        #pragma unroll
        for (int r = 0; r < 4; ++r) {
            pa[r] = fmaf(acc[ct][r], asv[ct], pa[r]);
            pd[r] = fmaf(acc[ct][r], adv[ct], pd[r]);
        }
    #pragma unroll
    for (int r = 0; r < 4; ++r) {
        #pragma unroll
        for (int d = 1; d <= 8; d <<= 1) {
            pa[r] += __shfl_xor(pa[r], d);
            pd[r] += __shfl_xor(pd[r], d);
        }
    }
    if (n16 == 0) {
        #pragma unroll
        for (int r = 0; r < 4; ++r) {
            if (rowb + r < n) { as_[rowb + r] = pa[r]; ad_[rowb + r] = pd[r]; }
        }
    }

    _Float16* hh = (_Float16*)h16;
    #pragma unroll
    for (int r = 0; r < 4; ++r) {
        if (rowb + r < n) {
            #pragma unroll
            for (int ct = 0; ct < 4; ++ct)
                hh[(size_t)(rowb + r) * 64 + ct * 16 + n16] = (_Float16)acc[ct][r];
        }
    }
}

// ---------------- fused launch 2: [csr buckets | gemm layer 1] -------------

__global__ __launch_bounds__(256) void k_csr_gemm1(
    const unsigned* __restrict__ gout, const int* __restrict__ goff,
    int* __restrict__ csrc, int2* __restrict__ rowse, int nlb,
    const float* __restrict__ x, const float* __restrict__ W1,
    const float* __restrict__ a1s, const float* __restrict__ a1d,
    __half* __restrict__ h16, float* __restrict__ as_, float* __restrict__ ad_, int n)
{
    extern __shared__ __align__(16) char smem[];
    if (blockIdx.x < NBKT)
        csr_body(smem, blockIdx.x, gout, goff, csrc, rowse, n, nlb);
    else
        gemm_body<128, float>(smem, blockIdx.x - NBKT, x, W1, a1s, a1d, h16, as_, ad_, n);
}

__global__ __launch_bounds__(256) void k_gemm2(
    const __half* __restrict__ xh, const float* __restrict__ W2,
    const float* __restrict__ a2s, const float* __restrict__ a2d,
    __half* __restrict__ h16, float* __restrict__ as_, float* __restrict__ ad_, int n)
{
    extern __shared__ __align__(16) char smem[];
    gemm_body<64, _Float16>(smem, blockIdx.x, (const _Float16*)xh, W2, a2s, a2d, h16, as_, ad_, n);
}

// ---------------- per-dst aggregation (two nodes per wave) -----------------
// Offset/weight broadcast via __shfl (ds_bpermute) instead of LDS.

template <bool RELU, typename OT>
__device__ __forceinline__ void agg_one(
    int node, int lane,
    const int2* __restrict__ rowse,
    const int* __restrict__ csrc, const __half* __restrict__ h16,
    const float* __restrict__ as_, const float* __restrict__ ad_,
    const float* __restrict__ bias, OT* __restrict__ out)
{
    const int2 se = rowse[node];
    const int start = se.x;
    const int end   = se.y;
    const int deg   = end - start;
    const float adn = ad_[node];

    if (deg <= 64) {
        int s = 0;
        if (lane < deg) s = csrc[start + lane];
        const int myoff = s << 6;

        const int g  = lane >> 3;
        const int fl = (lane & 7) << 3;
        const __half* __restrict__ hf = h16 + fl;
        const int niter = (deg + 7) >> 3;

        uint4 v[8];
        #pragma unroll
        for (int j = 0; j < 8; ++j) {
            if (j < niter)
                v[j] = *(const uint4*)(hf + SHF(myoff, (j << 3) + g));
        }

        float e = -1e30f;
        if (lane < deg) e = leaky(as_[s] + adn);
        float w = __expf(e);            // pad lanes: exp(-1e30)=0
        float dsum = w;
        #pragma unroll
        for (int d = 32; d >= 1; d >>= 1) dsum += __shfl_xor(dsum, d);

        float af[8] = {0.f, 0.f, 0.f, 0.f, 0.f, 0.f, 0.f, 0.f};
        #pragma unroll
        for (int j = 0; j < 8; ++j) {
            if (j < niter) {
                float wj = SHF(w, (j << 3) + g);
                unsigned uu[4] = {v[j].x, v[j].y, v[j].z, v[j].w};
                #pragma unroll
                for (int q = 0; q < 4; ++q) {
                    __half2 h2 = *(__half2*)&uu[q];
                    float2 f2 = __half22float2(h2);
                    af[2 * q]     = fmaf(wj, f2.x, af[2 * q]);
                    af[2 * q + 1] = fmaf(wj, f2.y, af[2 * q + 1]);
                }
            }
        }
        #pragma unroll
        for (int q = 0; q < 8; ++q) {
            af[q] += __shfl_xor(af[q], 8);
            af[q] += __shfl_xor(af[q], 16);
            af[q] += __shfl_xor(af[q], 32);
        }
        if (g == 0) {
            float inv = 1.f / dsum;
            float4 b0 = *(const float4*)(bias + fl);
            float4 b1 = *(const float4*)(bias + fl + 4);
            float o[8] = { fmaf(af[0], inv, b0.x), fmaf(af[1], inv, b0.y),
                           fmaf(af[2], inv, b0.z), fmaf(af[3], inv, b0.w),
                           fmaf(af[4], inv, b1.x), fmaf(af[5], inv, b1.y),
                           fmaf(af[6], inv, b1.z), fmaf(af[7], inv, b1.w) };
            if (RELU) {
                #pragma unroll
                for (int q = 0; q < 8; ++q) o[q] = fmaxf(o[q], 0.f);
            }
            if constexpr (sizeof(OT) == 2) {
                __half* op = (__half*)out + (size_t)node * 64 + fl;
                __half2 p0 = __floats2half2_rn(o[0], o[1]);
                __half2 p1 = __floats2half2_rn(o[2], o[3]);
                __half2 p2 = __floats2half2_rn(o[4], o[5]);
                __half2 p3 = __floats2half2_rn(o[6], o[7]);
                uint4 pk = { *(unsigned*)&p0, *(unsigned*)&p1, *(unsigned*)&p2, *(unsigned*)&p3 };
                *(uint4*)op = pk;
            } else {
                float* op = (float*)out + (size_t)node * 64 + fl;
                *(float4*)op       = make_float4(o[0], o[1], o[2], o[3]);
                *(float4*)(op + 4) = make_float4(o[4], o[5], o[6], o[7]);
            }
        }
    } else {
        const __half* __restrict__ hp = h16 + lane;
        float m = -1e30f;
        for (int base = start; base < end; base += 64) {
            int idx = base + lane;
            if (idx < end) m = fmaxf(m, leaky(as_[csrc[idx]] + adn));
        }
        #pragma unroll
        for (int d = 32; d >= 1; d >>= 1) m = fmaxf(m, __shfl_xor(m, d));

        float acc0 = 0.f, acc1 = 0.f, acc2 = 0.f, acc3 = 0.f, dsum = 0.f;
        for (int base = start; base < end; base += 64) {
            int idx = base + lane;
            int s = 0; float w = 0.f;
            if (idx < end) {
                s = csrc[idx];
                w = __expf(leaky(as_[s] + adn) - m);
            }
            dsum += w;
            int off = s << 6;
            int wu = __float_as_uint(w);
            int cnt = min(64, end - base);
            int cr = (cnt + 3) & ~3;
            for (int j = 0; j < cr; j += 4) {
                int   o0 = RL(off, j + 0), o1 = RL(off, j + 1);
                int   o2 = RL(off, j + 2), o3 = RL(off, j + 3);
                float w0 = __uint_as_float(RL(wu, j + 0));
                float w1 = __uint_as_float(RL(wu, j + 1));
                float w2 = __uint_as_float(RL(wu, j + 2));
                float w3 = __uint_as_float(RL(wu, j + 3));
                float v0 = __half2float(hp[o0]), v1 = __half2float(hp[o1]);
                float v2 = __half2float(hp[o2]), v3 = __half2float(hp[o3]);
                acc0 = fmaf(w0, v0, acc0);
                acc1 = fmaf(w1, v1, acc1);
                acc2 = fmaf(w2, v2, acc2);
                acc3 = fmaf(w3, v3, acc3);
            }
        }
        #pragma unroll
        for (int d = 32; d >= 1; d >>= 1) dsum += __shfl_xor(dsum, d);
        float acc = (acc0 + acc1) + (acc2 + acc3);
        float o = acc / dsum + bias[lane];
        if (RELU) o = fmaxf(o, 0.f);
        if constexpr (sizeof(OT) == 2)
            ((__half*)out)[(size_t)node * 64 + lane] = __float2half(o);
        else
            ((float*)out)[(size_t)node * 64 + lane] = o;
    }
}

template <bool RELU, typename OT>
__global__ __launch_bounds__(256) void k_aggregate(
    const int2* __restrict__ rowse,
    const int* __restrict__ csrc,
    const __half* __restrict__ h16, const float* __restrict__ as_,
    const float* __restrict__ ad_, const float* __restrict__ bias,
    OT* __restrict__ out, int n)
{
    const int lane = threadIdx.x & 63;
    const int wid  = threadIdx.x >> 6;
    const int nodeA = (blockIdx.x * 4 + wid) * 2;
    if (nodeA >= n) return;

    const int half = lane >> 5;
    const int hl   = lane & 31;
    const int node = nodeA + half;           // n is even: nodeA+1 < n

    const int2 se = rowse[node];
    const float adn = ad_[node];             // independent: issue early
    const int start = se.x;
    const int deg   = se.y - se.x;
    const int mdeg  = max(deg, __shfl_xor(deg, 32));   // wave-uniform

    if (mdeg <= 32) {
        // ---- paired fast path: 32 lanes per node ----
        int s = 0;
        const bool act = hl < deg;
        if (act) s = csrc[start + hl];
        const int myoff = s << 6;

        const int g  = (lane >> 3) & 3;      // group within half
        const int fl = (lane & 7) << 3;      // feature octet
        const __half* __restrict__ hf = h16 + fl;
        int nit = (deg + 3) >> 2;            // 1..8
        nit = max(nit, __shfl_xor(nit, 32)); // wave-uniform

        // issue ALL h-row loads (offsets via bpermute, no LDS round trip)
        const int sbase = (half << 5) + g;
        uint4 v[8];
        #pragma unroll
        for (int j = 0; j < 8; ++j) {
            if (j < nit)
                v[j] = *(const uint4*)(hf + SHF(myoff, sbase + (j << 2)));
        }

        // w chain overlaps the in-flight h loads
        float e = -1e30f;                    // exp(-1e30) = 0 for pad lanes
        if (act) e = leaky(as_[s] + adn);
        float w = __expf(e);
        float dsum = w;
        #pragma unroll
        for (int d = 16; d >= 1; d >>= 1) dsum += __shfl_xor(dsum, d);

        float af[8] = {0.f, 0.f, 0.f, 0.f, 0.f, 0.f, 0.f, 0.f};
        #pragma unroll
        for (int j = 0; j < 8; ++j) {
            if (j < nit) {
                float wj = SHF(w, sbase + (j << 2));
                unsigned uu[4] = {v[j].x, v[j].y, v[j].z, v[j].w};
                #pragma unroll
                for (int q = 0; q < 4; ++q) {
                    __half2 h2 = *(__half2*)&uu[q];
                    float2 f2 = __half22float2(h2);
                    af[2 * q]     = fmaf(wj, f2.x, af[2 * q]);
                    af[2 * q + 1] = fmaf(wj, f2.y, af[2 * q + 1]);
                }
            }
        }
        #pragma unroll
        for (int q = 0; q < 8; ++q) {
            af[q] += __shfl_xor(af[q], 8);
            af[q] += __shfl_xor(af[q], 16);
        }
        if (g == 0) {                        // lanes 0-7 (A) and 32-39 (B)
            float inv = 1.f / dsum;
            float4 b0 = *(const float4*)(bias + fl);
            float4 b1 = *(const float4*)(bias + fl + 4);
            float o[8] = { fmaf(af[0], inv, b0.x), fmaf(af[1], inv, b0.y),
                           fmaf(af[2], inv, b0.z), fmaf(af[3], inv, b0.w),
                           fmaf(af[4], inv, b1.x), fmaf(af[5], inv, b1.y),
                           fmaf(af[6], inv, b1.z), fmaf(af[7], inv, b1.w) };
            if (RELU) {
                #pragma unroll
                for (int q = 0; q < 8; ++q) o[q] = fmaxf(o[q], 0.f);
            }
            if constexpr (sizeof(OT) == 2) {
                __half* op = (__half*)out + (size_t)node * 64 + fl;
                __half2 p0 = __floats2half2_rn(o[0], o[1]);
                __half2 p1 = __floats2half2_rn(o[2], o[3]);
                __half2 p2 = __floats2half2_rn(o[4], o[5]);
                __half2 p3 = __floats2half2_rn(o[6], o[7]);
                uint4 pk = { *(unsigned*)&p0, *(unsigned*)&p1, *(unsigned*)&p2, *(unsigned*)&p3 };
                *(uint4*)op = pk;
            } else {
                float* op = (float*)out + (size_t)node * 64 + fl;
                *(float4*)op       = make_float4(o[0], o[1], o[2], o[3]);
                *(float4*)(op + 4) = make_float4(o[4], o[5], o[6], o[7]);
            }
        }
    } else {
        agg_one<RELU, OT>(nodeA,     lane, rowse, csrc, h16, as_, ad_, bias, out);
        agg_one<RELU, OT>(nodeA + 1, lane, rowse, csrc, h16, as_, ad_, bias, out);
    }
}

// ---------------- launch ----------------

extern "C" void kernel_launch(void* const* d_in, const int* in_sizes, int n_in,
                              void* d_out, int out_size, void* d_ws, size_t ws_size,
                              hipStream_t stream) {
    const float* x   = (const float*)d_in[0];
    const int*   ei  = (const int*)  d_in[1];   // [2, E]: src row 0, dst row 1
    const float* W1  = (const float*)d_in[2];
    const float* a1s = (const float*)d_in[3];
    const float* a1d = (const float*)d_in[4];
    const float* b1  = (const float*)d_in[5];
    const float* W2  = (const float*)d_in[6];
    const float* a2s = (const float*)d_in[7];
    const float* a2d = (const float*)d_in[8];
    const float* b2  = (const float*)d_in[9];
    float* out = (float*)d_out;

    const int N_ = NNODES, E_ = NEDGES;
    const int NLB = (E_ + CHUNK - 1) / CHUNK;   // 391

    char* ws = (char*)d_ws;
    size_t off = 0;
    auto alloc = [&](size_t bytes) -> void* {
        void* p = ws + off;
        off += (bytes + 255) & ~(size_t)255;
        return p;
    };
    int*      csrc     = (int*)alloc((size_t)NBKT * REGS * 4);     // 5.24 MB
    int2*     rowse    = (int2*)alloc((size_t)N_ * 8);
    float*    as_      = (float*)alloc((size_t)N_ * 4);
    float*    ad_      = (float*)alloc((size_t)N_ * 4);
    __half*   h16      = (__half*)alloc((size_t)N_ * FOUT * 2);    // 6.4 MB
    __half*   xr2h     = (__half*)alloc((size_t)N_ * FOUT * 2);    // 6.4 MB
    unsigned* gout     = (unsigned*)alloc((size_t)E_ * 4);         // 3.2 MB
    int*      goff     = (int*)alloc((size_t)NLB * (NBKT + 1) * 4);

    constexpr unsigned SM_G1 = 64 * (128 + 8) * 2 + 128 * 64 * 2;  // 33792 B (>= csr carve)
    constexpr unsigned SM_G2 = 64 * (64 + 8) * 2  + 64 * 64 * 2;   // 17408 B

    const int GB = (N_ + 63) / 64;     // 782 gemm blocks
    const int AB = (N_ / 2 + 3) / 4;   // 6250 aggregate blocks (2 nodes/wave)

    k_localsort<<<NLB, 256, 0, stream>>>(ei, gout, goff, E_);
    k_csr_gemm1<<<NBKT + GB, 256, SM_G1, stream>>>(gout, goff, csrc, rowse, NLB,
                                                   x, W1, a1s, a1d, h16, as_, ad_, N_);
    k_aggregate<true,  __half><<<AB, 256, 0, stream>>>(rowse, csrc, h16, as_, ad_, b1, xr2h, N_);
    k_gemm2<<<GB, 256, SM_G2, stream>>>(xr2h, W2, a2s, a2d, h16, as_, ad_, N_);
    k_aggregate<false, float ><<<AB, 256, 0, stream>>>(rowse, csrc, h16, as_, ad_, b2, out, N_);
}